// Round 18
// baseline (5891.521 us; speedup 1.0000x reference)
//
#include <hip/hip_runtime.h>

// LSTMFromEmbeddings: B=128, T=1024, E=256, H=256, C=2, bidirectional + meanpool + linear.
//
// R17 = dual-chain over the lean R14 body. R14 step (1536ns) is mostly EXPOSED LATENCY
// (exchange RT + chained MFMA/LDS/trans), not throughput-compute (~300ns) — a second
// independent chain (same dir, second batch-block; weights shared) fills the bubbles.
// Bounded downside: if step were pure serial compute, dual == 2x single == R14 total.
//  rec: 32 wgs x 512thr; wg = member m(0..3) of pair {(d,2p),(d,2p+1)} (co-XCD mod 8).
//       Per parity-step: gloads | hhA,ewA,pubA | hhB,ewB,pubB | xgA | xgB |
//       pollA+pollB (batched, issued together) | unpack | ONE lgkm barrier.
//       Per-chain sync (tagged parity words, late poll, batched retry) == R14.
//  prep: bf16(x*mask) image in B-fragment layout (rotation swizzle pre-applied).
//  head: out = (hsum/1024) @ W_lin^T + b_lin.

#define B_ 128
#define T_ 1024
#define E_ 256
#define H_ 256

typedef short short8 __attribute__((ext_vector_type(8)));
typedef float f32x4 __attribute__((ext_vector_type(4)));
typedef float f32x2 __attribute__((ext_vector_type(2)));

__device__ __forceinline__ unsigned short f2bf(float f) {
  unsigned u = __builtin_bit_cast(unsigned, f);
  u += 0x7fffu + ((u >> 16) & 1u);  // RNE
  return (unsigned short)(u >> 16);
}
__device__ __forceinline__ f32x4 mfma16(short8 a, short8 b, f32x4 c) {
  return __builtin_amdgcn_mfma_f32_16x16x32_bf16(a, b, c, 0, 0, 0);
}
__device__ __forceinline__ float rcpf(float x) { return __builtin_amdgcn_rcpf(x); }

// proven R8 elementwise: 5 exp + 3 rcp per unit
__device__ __forceinline__ float lstm_ew(float gi, float gf, float gg, float go, float& c) {
  float ei = __expf(-gi), ef = __expf(-gf), eg = __expf(-2.f * gg);
  float di = 1.f + ei, df = 1.f + ef, dg = 1.f + eg;
  float r1 = rcpf(di * dg);
  float si = r1 * dg;
  float tg = 2.f * (r1 * di) - 1.f;
  c = rcpf(df) * c + si * tg;
  float eo = __expf(-go), ec = __expf(2.f * c);
  float do_ = 1.f + eo, dc = 1.f + ec;
  float r3 = rcpf(do_ * dc);
  float so = r3 * dc;
  float th = 1.f - 2.f * (r3 * do_);
  return so * th;
}

__device__ __forceinline__ short8 cvt8(f32x4 v0, f32x4 v1) {
  short8 o;
  o[0] = (short)f2bf(v0[0]); o[1] = (short)f2bf(v0[1]);
  o[2] = (short)f2bf(v0[2]); o[3] = (short)f2bf(v0[3]);
  o[4] = (short)f2bf(v1[0]); o[5] = (short)f2bf(v1[1]);
  o[6] = (short)f2bf(v1[2]); o[7] = (short)f2bf(v1[3]);
  return o;
}

__device__ __forceinline__ void bar_lds() {  // LDS-only barrier; vmem stays in flight
  asm volatile("s_waitcnt lgkmcnt(0)" ::: "memory");
  __builtin_amdgcn_s_barrier();
}

__device__ __forceinline__ void gload16(const void* g, void* l) {
  __builtin_amdgcn_global_load_lds(
      (const __attribute__((address_space(1))) void*)g,
      (__attribute__((address_space(3))) void*)l, 16, 0, 0);
}

// ---------------- prep: x image in B-fragment layout (rotation swizzle) ------
// word gid = (bblk*1024 + t)*512 + r*32 + s; slot s holds chunk (s - r) & 31.
__global__ __launch_bounds__(256, 4) void prep_kernel(
    const float* __restrict__ x, const float* __restrict__ mask,
    unsigned short* __restrict__ img) {
  int gid = blockIdx.x * 256 + threadIdx.x;
  int i = gid & 511;
  int tt = (gid >> 9) & 1023;
  int bblk = gid >> 19;
  int r = i >> 5, s = i & 31, kc = (s - r) & 31;
  int b = bblk * 16 + r;
  const f32x4* src = (const f32x4*)(x + ((size_t)b * T_ + tt) * E_ + kc * 8);
  float mk = mask[(size_t)b * T_ + tt];
  ((short8*)img)[gid] = cvt8(src[0] * mk, src[1] * mk);
}

// chain sub-blocks -------------------------------------------------------------
#define HH16(HSRC, AC, AC2, WREG)                                               \
  {                                                                             \
    const char* hsP = (const char*)(HSRC);                                      \
    _Pragma("unroll") for (int kp = 0; kp < 4; ++kp) {                          \
      short8 b0 = *(const short8*)(hsP + ro[2 * kp]);                           \
      short8 b1 = *(const short8*)(hsP + ro[2 * kp + 1]);                       \
      AC[0] = mfma16(WREG[0][2 * kp], b0, AC[0]);                               \
      AC[1] = mfma16(WREG[1][2 * kp], b0, AC[1]);                               \
      AC2[0] = mfma16(WREG[0][2 * kp + 1], b1, AC2[0]);                         \
      AC2[1] = mfma16(WREG[1][2 * kp + 1], b1, AC2[1]);                         \
    }                                                                           \
  }

#define POLL_ISSUE(HB, V)                                                        \
  V[0] = __hip_atomic_load(&(HB)[p0], __ATOMIC_RELAXED, __HIP_MEMORY_SCOPE_AGENT); \
  V[1] = __hip_atomic_load(&(HB)[p1], __ATOMIC_RELAXED, __HIP_MEMORY_SCOPE_AGENT); \
  V[2] = __hip_atomic_load(&(HB)[p2], __ATOMIC_RELAXED, __HIP_MEMORY_SCOPE_AGENT);

#define POLL_RETRY(HB, V, TAG)                                                   \
  while (((unsigned)(V[0] >> 32) != (TAG)) | ((unsigned)(V[1] >> 32) != (TAG)) | \
         ((unsigned)(V[2] >> 32) != (TAG))) {                                    \
    if ((unsigned)(V[0] >> 32) != (TAG))                                         \
      V[0] = __hip_atomic_load(&(HB)[p0], __ATOMIC_RELAXED, __HIP_MEMORY_SCOPE_AGENT); \
    if ((unsigned)(V[1] >> 32) != (TAG))                                         \
      V[1] = __hip_atomic_load(&(HB)[p1], __ATOMIC_RELAXED, __HIP_MEMORY_SCOPE_AGENT); \
    if ((unsigned)(V[2] >> 32) != (TAG))                                         \
      V[2] = __hip_atomic_load(&(HB)[p2], __ATOMIC_RELAXED, __HIP_MEMORY_SCOPE_AGENT); \
    asm volatile("" ::: "memory");                                               \
  }

// step body, compile-time parity PAR (2 chain-steps per invocation pair).
#define REC2(PAR, TT, MORE_)                                                    \
  {                                                                             \
    const bool more_ = (MORE_);                                                 \
    if constexpr (PREP) {                                                       \
      if ((TT) + 2 < T_) {                                                      \
        gload16(gsrcA, (char*)XSa[PAR] + w * 1024);                             \
        gload16(gsrcB, (char*)XSb[PAR] + w * 1024);                             \
        gsrcA += dstep;                                                         \
        gsrcB += dstep;                                                         \
      }                                                                         \
    }                                                                           \
    f32x4 xva0, xva1, xvb0, xvb1;                                               \
    float mka = 0.f, mkb = 0.f;                                                 \
    if constexpr (!PREP) {                                                      \
      if (more_) {                                                              \
        int ts = d ? (T_ - 2 - (TT)) : ((TT) + 1);                              \
        const float* xrA = x + ((size_t)gbA_s * T_ + ts) * E_;                  \
        xva0 = ((const f32x4*)(xrA + kcs * 8))[0];                              \
        xva1 = ((const f32x4*)(xrA + kcs * 8))[1];                              \
        mka = mask[(size_t)gbA_s * T_ + ts];                                    \
        const float* xrB = x + ((size_t)gbB_s * T_ + ts) * E_;                  \
        xvb0 = ((const f32x4*)(xrB + kcs * 8))[0];                              \
        xvb1 = ((const f32x4*)(xrB + kcs * 8))[1];                              \
        mkb = mask[(size_t)gbB_s * T_ + ts];                                    \
      }                                                                         \
    }                                                                           \
    const unsigned tag = (unsigned)((TT) + 1);                                  \
    unsigned long long* __restrict__ hbA = (PAR) ? HbA0 : HbA1;                 \
    unsigned long long* __restrict__ hbB = (PAR) ? HbB0 : HbB1;                 \
    /* chain A: hh + ew + publish + own-HS */                                   \
    HH16(HSa[PAR], accA, accA2, wh);                                            \
    float h0A = lstm_ew(accA[0][0] + accA2[0][0], accA[0][1] + accA2[0][1],     \
                        accA[0][2] + accA2[0][2], accA[0][3] + accA2[0][3], csA[0]); \
    float h1A = lstm_ew(accA[1][0] + accA2[1][0], accA[1][1] + accA2[1][1],     \
                        accA[1][2] + accA2[1][2], accA[1][3] + accA2[1][3], csA[1]); \
    hsA[0] += h0A;                                                              \
    hsA[1] += h1A;                                                              \
    unsigned payA;                                                              \
    if (more_) {                                                                \
      asm("v_cvt_pk_bf16_f32 %0, %1, %2" : "=v"(payA) : "v"(h0A), "v"(h1A));    \
      unsigned long long wrd = (((unsigned long long)tag) << 32) | (unsigned long long)payA; \
      __hip_atomic_store(&hbA[pubIdx], wrd, __ATOMIC_RELAXED,                   \
                         __HIP_MEMORY_SCOPE_AGENT);                             \
      asm volatile("" ::: "memory");                                            \
      *(int*)((char*)HSa[1 - (PAR)] + ownOff) = (int)payA;                      \
    }                                                                           \
    /* chain B: hh + ew + publish + own-HS */                                   \
    HH16(HSb[PAR], accB_, accB2, wh);                                           \
    float h0B = lstm_ew(accB_[0][0] + accB2[0][0], accB_[0][1] + accB2[0][1],   \
                        accB_[0][2] + accB2[0][2], accB_[0][3] + accB2[0][3], csB[0]); \
    float h1B = lstm_ew(accB_[1][0] + accB2[1][0], accB_[1][1] + accB2[1][1],   \
                        accB_[1][2] + accB2[1][2], accB_[1][3] + accB2[1][3], csB[1]); \
    hsB[0] += h0B;                                                              \
    hsB[1] += h1B;                                                              \
    if (more_) {                                                                \
      unsigned payB;                                                            \
      asm("v_cvt_pk_bf16_f32 %0, %1, %2" : "=v"(payB) : "v"(h0B), "v"(h1B));    \
      unsigned long long wrd = (((unsigned long long)tag) << 32) | (unsigned long long)payB; \
      __hip_atomic_store(&hbB[pubIdx], wrd, __ATOMIC_RELAXED,                   \
                         __HIP_MEMORY_SCOPE_AGENT);                             \
      asm volatile("" ::: "memory");                                            \
      *(int*)((char*)HSb[1 - (PAR)] + ownOff) = (int)payB;                      \
      if constexpr (!PREP) {                                                    \
        ((short8*)XSa[1 - (PAR)])[st_r * 32 + ((st_s + st_r) & 31)] =           \
            cvt8(xva0 * mka, xva1 * mka);                                       \
        ((short8*)XSb[1 - (PAR)])[st_r * 32 + ((st_s + st_r) & 31)] =           \
            cvt8(xvb0 * mkb, xvb1 * mkb);                                       \
        bar_lds();                                                              \
      }                                                                         \
      /* xgA then xgB (fills both publish->poll windows) */                     \
      accA[0] = bias4[0];                                                       \
      accA[1] = bias4[1];                                                       \
      accA2[0] = (f32x4){0.f, 0.f, 0.f, 0.f};                                   \
      accA2[1] = (f32x4){0.f, 0.f, 0.f, 0.f};                                   \
      HH16(XSa[1 - (PAR)], accA, accA2, wi);                                    \
      accB_[0] = bias4[0];                                                      \
      accB_[1] = bias4[1];                                                      \
      accB2[0] = (f32x4){0.f, 0.f, 0.f, 0.f};                                   \
      accB2[1] = (f32x4){0.f, 0.f, 0.f, 0.f};                                   \
      HH16(XSb[1 - (PAR)], accB_, accB2, wi);                                   \
      /* polls: issue both first attempts together, then retry A, then B */     \
      unsigned long long vA[3], vB[3];                                          \
      POLL_ISSUE(hbA, vA);                                                      \
      POLL_ISSUE(hbB, vB);                                                      \
      asm volatile("" ::: "memory");                                            \
      POLL_RETRY(hbA, vA, tag);                                                 \
      {                                                                         \
        char* hw = (char*)HSa[1 - (PAR)];                                       \
        *(int*)(hw + uo0) = (int)(unsigned)vA[0];                               \
        *(int*)(hw + uo1) = (int)(unsigned)vA[1];                               \
        *(int*)(hw + uo2) = (int)(unsigned)vA[2];                               \
      }                                                                         \
      POLL_RETRY(hbB, vB, tag);                                                 \
      {                                                                         \
        char* hw = (char*)HSb[1 - (PAR)];                                       \
        *(int*)(hw + uo0) = (int)(unsigned)vB[0];                               \
        *(int*)(hw + uo1) = (int)(unsigned)vB[1];                               \
        *(int*)(hw + uo2) = (int)(unsigned)vB[2];                               \
      }                                                                         \
      bar_lds();                                                                \
    }                                                                           \
  }

// ---------------- rec: dual-chain fused projection + recurrence ---------------
// grid 32, 512 threads. p8 = bid & 7 -> d = p8>>2, pair = p8&3; m = bid >> 3
// (members co-XCD: bids congruent mod 8). Member m owns units [m*64, m*64+64).
// A-row map (R13): tile T = 2w+i, row l15: gate = l15&3, unit = w*8+(l15>>2)*2+i;
// D: acc[i][r] = gate r of unit w*8+l4*2+i, batch l15.
template <bool PREP>
__global__ __launch_bounds__(512, 1) void rec_kernel(
    const float* __restrict__ x, const float* __restrict__ mask,
    const unsigned short* __restrict__ img,
    const float* __restrict__ WihF, const float* __restrict__ WhhF,
    const float* __restrict__ bF, const float* __restrict__ WihB,
    const float* __restrict__ WhhB, const float* __restrict__ bB,
    unsigned long long* __restrict__ Hbuf, float* __restrict__ hsum) {
  __shared__ __align__(16) short XSa[2][16 * 256], XSb[2][16 * 256];  // 32KB
  __shared__ __align__(16) short HSa[2][16 * 256], HSb[2][16 * 256];  // 32KB

  const int bid = blockIdx.x;
  const int p8 = bid & 7, m = bid >> 3;
  const int d = p8 >> 2, pair = p8 & 3;
  const int bblkA = 2 * pair, bblkB = 2 * pair + 1;
  const int gA = d * 8 + bblkA, gB = d * 8 + bblkB;
  const int tid = threadIdx.x;
  const int w = tid >> 6, l = tid & 63, l15 = l & 15, l4 = l >> 4;

  // fallback staging: thread covers slot tid&31 of row tid>>5 (one 16B per chain)
  const int st_r = tid >> 5, st_s = tid & 31;
  const int kcs = (st_s - st_r) & 31;
  const int gbA_s = bblkA * 16 + st_r, gbB_s = bblkB * 16 + st_r;

  const float* Wih = d ? WihB : WihF;
  const float* Whh = d ? WhhB : WhhF;
  const float* bias = d ? bB : bF;

  // ---- weight A-fragments -> registers (R13 row map; shared by both chains) --
  short8 wi[2][8], wh[2][8];
#pragma unroll
  for (int i = 0; i < 2; ++i) {
    int u_row = w * 8 + (l15 >> 2) * 2 + i;
    size_t nat = (size_t)((l15 & 3) * 256 + m * 64 + u_row);
#pragma unroll
    for (int kb = 0; kb < 8; ++kb) {
      const f32x4* pi = (const f32x4*)(Wih + nat * E_ + kb * 32 + l4 * 8);
      wi[i][kb] = cvt8(pi[0], pi[1]);
      const f32x4* ph = (const f32x4*)(Whh + nat * H_ + kb * 32 + l4 * 8);
      wh[i][kb] = cvt8(ph[0], ph[1]);
    }
  }
  f32x4 bias4[2];
#pragma unroll
  for (int i = 0; i < 2; ++i)
#pragma unroll
    for (int r = 0; r < 4; ++r)
      bias4[i][r] = bias[r * 256 + m * 64 + w * 8 + l4 * 2 + i];

  // ---- precomputed lane constants (identical to R14) ----
  int ro[8];
#pragma unroll
  for (int kp = 0; kp < 4; ++kp) {
    ro[2 * kp] = l15 * 512 + ((((kp * 8 + l4) + l15) & 31) << 4);
    ro[2 * kp + 1] = l15 * 512 + ((((kp * 8 + 4 + l4) + l15) & 31) << 4);
  }
  const int pubIdx = (m * 32 + w * 4 + l4) * 16 + l15;
  const int ownOff = l15 * 512 + ((((m * 8 + w) + l15) & 31) << 4) + l4 * 4;
  int pp = tid * 3;
  const int p0 = pp + (pp >= m * 512 ? 512 : 0);
  const int p1 = pp + 1 + (pp + 1 >= m * 512 ? 512 : 0);
  const int p2 = pp + 2 + (pp + 2 >= m * 512 ? 512 : 0);
#define UOFF(p) (((p) & 15) * 512 + (((((p) >> 6) + ((p) & 15)) & 31) << 4) + ((((p) >> 4) & 3) * 4))
  const int uo0 = UOFF(p0), uo1 = UOFF(p1), uo2 = UOFF(p2);
#undef UOFF
  unsigned long long* __restrict__ HbA0 = Hbuf + ((size_t)gA * 2 + 0) * 2048;
  unsigned long long* __restrict__ HbA1 = Hbuf + ((size_t)gA * 2 + 1) * 2048;
  unsigned long long* __restrict__ HbB0 = Hbuf + ((size_t)gB * 2 + 0) * 2048;
  unsigned long long* __restrict__ HbB1 = Hbuf + ((size_t)gB * 2 + 1) * 2048;

  // img tile pointers
  const int dstep = d ? -8192 : 8192;
  const char* imgB = (const char*)img;
  const char* gsrcA = imgB + ((size_t)(bblkA * 1024 + (d ? (T_ - 1) : 0))) * 8192 +
                      (size_t)tid * 16;
  const char* gsrcB = imgB + ((size_t)(bblkB * 1024 + (d ? (T_ - 1) : 0))) * 8192 +
                      (size_t)tid * 16;

  // ---- prologue: HS*[0]=0; stage x_0,x_1 both chains; acc = bias + xg_0 ------
  ((int4*)HSa)[tid] = (int4){0, 0, 0, 0};
  ((int4*)HSb)[tid] = (int4){0, 0, 0, 0};
  if constexpr (PREP) {
    gload16(gsrcA, (char*)XSa[0] + w * 1024);
    gload16(gsrcA + dstep, (char*)XSa[1] + w * 1024);
    gsrcA += 2 * dstep;
    gload16(gsrcB, (char*)XSb[0] + w * 1024);
    gload16(gsrcB + dstep, (char*)XSb[1] + w * 1024);
    gsrcB += 2 * dstep;
  } else {
    int ts = d ? (T_ - 1) : 0;
    const float* xrA = x + ((size_t)gbA_s * T_ + ts) * E_;
    float mka = mask[(size_t)gbA_s * T_ + ts];
    ((short8*)XSa[0])[st_r * 32 + ((st_s + st_r) & 31)] =
        cvt8(((const f32x4*)(xrA + kcs * 8))[0] * mka,
             ((const f32x4*)(xrA + kcs * 8))[1] * mka);
    const float* xrB = x + ((size_t)gbB_s * T_ + ts) * E_;
    float mkb = mask[(size_t)gbB_s * T_ + ts];
    ((short8*)XSb[0])[st_r * 32 + ((st_s + st_r) & 31)] =
        cvt8(((const f32x4*)(xrB + kcs * 8))[0] * mkb,
             ((const f32x4*)(xrB + kcs * 8))[1] * mkb);
  }
  __syncthreads();  // drains gloads + HS zeros visible

  f32x4 accA[2], accA2[2], accB_[2], accB2[2];
  accA[0] = bias4[0];
  accA[1] = bias4[1];
  accA2[0] = (f32x4){0.f, 0.f, 0.f, 0.f};
  accA2[1] = (f32x4){0.f, 0.f, 0.f, 0.f};
  HH16(XSa[0], accA, accA2, wi);
  accB_[0] = bias4[0];
  accB_[1] = bias4[1];
  accB2[0] = (f32x4){0.f, 0.f, 0.f, 0.f};
  accB2[1] = (f32x4){0.f, 0.f, 0.f, 0.f};
  HH16(XSb[0], accB_, accB2, wi);
  __syncthreads();  // XS*[0] consumed before first in-loop gload overwrites

  float csA[2] = {0.f, 0.f}, hsA[2] = {0.f, 0.f};
  float csB[2] = {0.f, 0.f}, hsB[2] = {0.f, 0.f};

  for (int t2 = 0; t2 < 511; ++t2) {
    const int tt = t2 * 2;
    REC2(0, tt, true);
    REC2(1, tt + 1, true);
  }
  REC2(0, 1022, true);
  REC2(1, 1023, false);

  // pooled sums: lane owns (batch bblk*16+l15, units gu, gu+1) per chain
  {
    int gu = m * 64 + w * 8 + l4 * 2;
    *(f32x2*)(hsum + ((size_t)d * B_ + bblkA * 16 + l15) * H_ + gu) =
        (f32x2){hsA[0], hsA[1]};
    *(f32x2*)(hsum + ((size_t)d * B_ + bblkB * 16 + l15) * H_ + gu) =
        (f32x2){hsB[0], hsB[1]};
  }
}

// ---------------- head: linear ----------------------------------------------
__global__ __launch_bounds__(256, 1) void head_kernel(
    const float* __restrict__ hsum, const float* __restrict__ Wlin,
    const float* __restrict__ blin, float* __restrict__ out) {
  int tid = threadIdx.x;  // 256 = 128 b x 2 c
  int b = tid >> 1, c = tid & 1;
  const f32x4* hf = (const f32x4*)(hsum + (size_t)b * H_);
  const f32x4* hbk = (const f32x4*)(hsum + (size_t)B_ * H_ + (size_t)b * H_);
  const f32x4* wl = (const f32x4*)(Wlin + (size_t)c * 512);
  float s = 0.f;
  for (int j = 0; j < 64; ++j) {
    f32x4 a = hf[j], ww = wl[j];
    s += a[0] * ww[0] + a[1] * ww[1] + a[2] * ww[2] + a[3] * ww[3];
  }
  for (int j = 0; j < 64; ++j) {
    f32x4 a = hbk[j], ww = wl[64 + j];
    s += a[0] * ww[0] + a[1] * ww[1] + a[2] * ww[2] + a[3] * ww[3];
  }
  out[tid] = s * (1.0f / 1024.0f) + blin[c];
}

// ---------------- launch -----------------------------------------------------
extern "C" void kernel_launch(void* const* d_in, const int* in_sizes, int n_in,
                              void* d_out, int out_size, void* d_ws, size_t ws_size,
                              hipStream_t stream) {
  const float* emb = (const float*)d_in[0];
  const float* mask = (const float*)d_in[1];
  const float* Wih_f = (const float*)d_in[2];
  const float* Whh_f = (const float*)d_in[3];
  const float* b_f = (const float*)d_in[4];
  const float* Wih_b = (const float*)d_in[5];
  const float* Whh_b = (const float*)d_in[6];
  const float* b_b = (const float*)d_in[7];
  const float* Wlin = (const float*)d_in[8];
  const float* blin = (const float*)d_in[9];
  float* out = (float*)d_out;

  const size_t HBUF_BYTES = (size_t)16 * 2 * 2048 * 8;      // 512 KiB
  const size_t HSUM_BYTES = (size_t)2 * B_ * H_ * 4;        // 256 KiB
  const size_t IMG_BYTES = (size_t)8 * 1024 * 512 * 16;     // 64 MiB
  if (ws_size < HBUF_BYTES + HSUM_BYTES) return;
  const bool prep = ws_size >= HBUF_BYTES + HSUM_BYTES + IMG_BYTES;

  char* ws = (char*)d_ws;
  unsigned long long* Hbuf = (unsigned long long*)ws;
  float* hsum = (float*)(ws + HBUF_BYTES);
  unsigned short* img = (unsigned short*)(ws + HBUF_BYTES + HSUM_BYTES);

  (void)hipMemsetAsync(Hbuf, 0, HBUF_BYTES, stream);  // tags start at 1; replay-safe
  if (prep) {
    prep_kernel<<<16384, 256, 0, stream>>>(emb, mask, img);
    rec_kernel<true><<<32, 512, 0, stream>>>(emb, mask, img, Wih_f, Whh_f, b_f,
                                             Wih_b, Whh_b, b_b, Hbuf, hsum);
  } else {
    rec_kernel<false><<<32, 512, 0, stream>>>(emb, mask, img, Wih_f, Whh_f, b_f,
                                              Wih_b, Whh_b, b_b, Hbuf, hsum);
  }
  head_kernel<<<1, 256, 0, stream>>>(hsum, Wlin, blin, out);
}